// Round 15
// baseline (1166.429 us; speedup 1.0000x reference)
//
#include <hip/hip_runtime.h>
#include <hip/hip_bf16.h>

#define DD 128
#define CC 100000
#define BB 32
#define N_ITER 4
#define INV_INIT_NORM 0.125f   // 1/(sqrt(128)/sqrt(2)) = 1/8

typedef unsigned short u16;
typedef unsigned char  u8;
typedef __attribute__((ext_vector_type(8))) short  frag_ab;   // 8 bf16 (4 VGPRs)
typedef __attribute__((ext_vector_type(4))) float  f32x4;
typedef __attribute__((ext_vector_type(8))) unsigned short us8;
typedef __attribute__((ext_vector_type(4))) unsigned short us4;

__device__ __forceinline__ u16 f2bf(float f) {
    union { float f; unsigned u; } v; v.f = f;
    unsigned r = v.u + 0x7fff + ((v.u >> 16) & 1);   // RNE
    return (u16)(r >> 16);
}
__device__ __forceinline__ float bf2f(u16 h) {
    union { unsigned u; float f; } v; v.u = ((unsigned)h) << 16;
    return v.f;
}
// ---- OCP fp8 e4m3fn scalar converters (RNE, saturate at 448) ----
__device__ __forceinline__ u8 f2fp8(float f) {
    union { float f; unsigned u; } v; v.f = f;
    const u8 s = (u8)((v.u >> 24) & 0x80);
    const float a = fabsf(f);
    if (!(a < 464.f)) return s | 0x7E;                 // clamp (also NaN)
    if (a < 0.015625f) {                               // < 2^-6: subnormal
        int m = (int)(a * 512.0f + 0.5f);
        if (m > 7) return s | 0x08;
        return s | (u8)m;
    }
    const int ebits = (int)((v.u >> 23) & 0xFF) - 127;
    unsigned enc = ((unsigned)(ebits + 7) << 3) | ((v.u >> 20) & 0x7);
    const unsigned g = (v.u >> 19) & 1;
    const unsigned sticky = ((v.u & 0x7FFFF) != 0) ? 1u : 0u;
    const unsigned lsb = (v.u >> 20) & 1;
    enc += (g & (sticky | lsb));
    if (enc >= 0x7F) enc = 0x7E;
    return s | (u8)enc;
}
__device__ __forceinline__ float fp82f(u8 b) {
    const unsigned sgn = ((unsigned)(b & 0x80)) << 24;
    const unsigned e = (b >> 3) & 0xF, m = b & 7;
    union { unsigned u; float f; } v;
    if (e == 0) {
        v.f = (float)m * 0.001953125f;                 // m * 2^-9
        v.u |= sgn;
        return v.f;
    }
    v.u = sgn | ((e + 120) << 23) | (m << 20);
    return v.f;
}
// fast HW transcendentals: v_exp_f32 + v_rcp_f32
__device__ __forceinline__ float fsigmoid_(float x) {
    return __builtin_amdgcn_rcpf(1.0f + __expf(-x));
}
__device__ __forceinline__ float ftanh_(float x) {
    return 1.0f - 2.0f * __builtin_amdgcn_rcpf(1.0f + __expf(2.0f * x));
}

// ---------------- precompute: degrees / hierarchical scan / CSR fill ----------------

__global__ void ideg_kernel(const int* __restrict__ li, const int* __restrict__ ci,
                            int* __restrict__ idl, int* __restrict__ idc, int E) {
    int e = blockIdx.x * 256 + threadIdx.x;
    if (e < E) {
        atomicAdd(&idl[li[e]], 1);
        atomicAdd(&idc[ci[e]], 1);
    }
}

__global__ __launch_bounds__(1024)
void bsum_kernel(const int* __restrict__ deg, int* __restrict__ bsum, int n) {
    __shared__ int wred[16];
    const int tid = threadIdx.x, lane = tid & 63, wid = tid >> 6;
    int idx = blockIdx.x * 4096 + tid * 4;
    int s = 0;
#pragma unroll
    for (int j = 0; j < 4; ++j) if (idx + j < n) s += deg[idx + j];
#pragma unroll
    for (int o = 32; o > 0; o >>= 1) s += __shfl_down(s, o);
    if (lane == 0) wred[wid] = s;
    __syncthreads();
    if (tid == 0) {
        int t = 0;
#pragma unroll
        for (int k = 0; k < 16; ++k) t += wred[k];
        bsum[blockIdx.x] = t;
    }
}

__global__ __launch_bounds__(1024)
void scan2_kernel(const int* __restrict__ deg, const int* __restrict__ bsum,
                  int* __restrict__ off, int n, int nb) {
    __shared__ int wsum[16];
    __shared__ int carry_s;
    const int tid = threadIdx.x, lane = tid & 63, wid = tid >> 6;
    if (tid == 0) {
        int c = 0;
        for (int b = 0; b < blockIdx.x; ++b) c += bsum[b];
        carry_s = c;
    }
    int idx = blockIdx.x * 4096 + tid * 4;
    int v0 = idx     < n ? deg[idx]     : 0;
    int v1 = idx + 1 < n ? deg[idx + 1] : 0;
    int v2 = idx + 2 < n ? deg[idx + 2] : 0;
    int v3 = idx + 3 < n ? deg[idx + 3] : 0;
    int t = v0 + v1 + v2 + v3;
    int s = t;
#pragma unroll
    for (int o = 1; o < 64; o <<= 1) { int u = __shfl_up(s, o); if (lane >= o) s += u; }
    if (lane == 63) wsum[wid] = s;
    __syncthreads();
    if (wid == 0 && lane < 16) {
        int x = wsum[lane];
#pragma unroll
        for (int o = 1; o < 16; o <<= 1) { int u = __shfl_up(x, o); if (lane >= o) x += u; }
        wsum[lane] = x;
    }
    __syncthreads();
    int woff = (wid > 0) ? wsum[wid - 1] : 0;
    int excl = carry_s + woff + s - t;
    if (idx     < n) off[idx]     = excl;
    if (idx + 1 < n) off[idx + 1] = excl + v0;
    if (idx + 2 < n) off[idx + 2] = excl + v0 + v1;
    if (idx + 3 < n) off[idx + 3] = excl + v0 + v1 + v2;
    if (blockIdx.x == nb - 1 && tid == 0) off[n] = carry_s + wsum[15];
}

// both CSR fills in one launch
__global__ void fill2_kernel(const int* __restrict__ li, const int* __restrict__ ci,
                             const int* __restrict__ l_off, const int* __restrict__ c_off,
                             int* __restrict__ filll, int* __restrict__ fillc,
                             int* __restrict__ l_edges, int* __restrict__ c_edges, int E) {
    int e = blockIdx.x * 256 + threadIdx.x;
    if (e < E) {
        int l = li[e], c = ci[e];
        int pc = atomicAdd(&fillc[c], 1);
        c_edges[c_off[c] + pc] = l;
        int pl = atomicAdd(&filll[l], 1);
        l_edges[l_off[l] + pl] = c;
    }
}

// ---------------- precompute: weight folds / bf16 conversion ----------------

__global__ void foldw_kernel(const float* __restrict__ wih, int ldw,
                             const float* __restrict__ w2,
                             float* __restrict__ out, int out_ld, int M) {
    int idx = blockIdx.x * 256 + threadIdx.x;
    if (idx >= M * 128) return;
    int o = idx >> 7, k = idx & 127;
    float s = 0.f;
    for (int m = 0; m < 128; ++m) s += wih[(size_t)o * ldw + m] * w2[m * 128 + k];
    out[(size_t)o * out_ld + k] = s;
}

__global__ void foldb_kernel(const float* __restrict__ wih, int ldw,
                             const float* __restrict__ b2,
                             float* __restrict__ out, int M) {
    int o = blockIdx.x * 256 + threadIdx.x;
    if (o >= M) return;
    float s = 0.f;
    for (int m = 0; m < 128; ++m) s += wih[(size_t)o * ldw + m] * b2[m];
    out[o] = s;
}

// all 7 bf16 weight conversions in one launch
__global__ void cvtw_all_kernel(const float* __restrict__ s0, u16* __restrict__ d0,
                                const float* __restrict__ s1, u16* __restrict__ d1,
                                const float* __restrict__ s2, u16* __restrict__ d2,
                                const float* __restrict__ s3, u16* __restrict__ d3,
                                const float* __restrict__ s4, u16* __restrict__ d4,
                                const float* __restrict__ s5, u16* __restrict__ d5,
                                const float* __restrict__ s6, u16* __restrict__ d6) {
    int i = blockIdx.x * 256 + threadIdx.x;
    if      (i < 16384)   d0[i] = f2bf(s0[i]);
    else if (i < 32768)   d1[i - 16384] = f2bf(s1[i - 16384]);
    else if (i < 49152)   d2[i - 32768] = f2bf(s2[i - 32768]);
    else if (i < 98304)   d3[i - 49152] = f2bf(s3[i - 49152]);
    else if (i < 147456)  d4[i - 98304] = f2bf(s4[i - 98304]);
    else if (i < 196608)  d5[i - 147456] = f2bf(s5[i - 147456]);
    else if (i < 294912)  d6[i - 196608] = f2bf(s6[i - 196608]);
}

// both embedding inits in one launch
__global__ void init_emb2_kernel(const float* __restrict__ li, u16* __restrict__ lo, int nl,
                                 const float* __restrict__ ci, u16* __restrict__ co, int nc) {
    int i = blockIdx.x * 256 + threadIdx.x;
    if (i < nl) lo[i] = f2bf(li[i & (DD - 1)] * INV_INIT_NORM);
    else if (i < nl + nc) { int j = i - nl; co[j] = f2bf(ci[j & (DD - 1)] * INV_INIT_NORM); }
}

// ---------------- bf16 MFMA GEMM (msg MLP + readout) ----------------
// OUT: 0 = f32, 1 = bf16, 2 = fp8(e4m3).  XCD-aware row swizzle (R11).

template<bool RELU, int OUT>
__global__ __launch_bounds__(256)
void mfma_gemm(const u16* __restrict__ Ahi, const u16* __restrict__ Whi,
               const float* __restrict__ bias, void* __restrict__ Yv, int N, int M,
               int nbrow) {
    __shared__ u16 Ah[4][128][8], Wh[4][128][8];

    const int xcd = blockIdx.x & 7, tt = blockIdx.x >> 3;
    const int s2 = tt & 1, q = tt >> 1;
    const int brow = (xcd + 8 * q) * 2 + s2;
    if (brow >= nbrow) return;   // uniform early-out before any barrier

    const int tid = threadIdx.x;
    const int bn = brow * 128, bm = blockIdx.y * 128;
    const int l = tid & 63, w = tid >> 6;
    const int wr = w >> 1, wc = w & 1;
    const int lr = l & 15, lg = l >> 4;

    f32x4 acc[4][4];
#pragma unroll
    for (int i = 0; i < 4; ++i)
#pragma unroll
        for (int j = 0; j < 4; ++j) acc[i][j] = (f32x4){0.f, 0.f, 0.f, 0.f};

    for (int k0 = 0; k0 < 128; k0 += 32) {
#pragma unroll
        for (int t = 0; t < 2; ++t) {
            const int slot = t * 256 + tid;
            const int row = slot >> 2, g = slot & 3, rs = row ^ (g << 1);
            const int gr = bn + row;
            us8 vh = (us8)0;
            if (gr < N) vh = *(const us8*)(Ahi + (size_t)gr * 128 + k0 + g * 8);
            *(us8*)&Ah[g][rs][0] = vh;
            *(us8*)&Wh[g][rs][0] = *(const us8*)(Whi + (size_t)(bm + row) * 128 + k0 + g * 8);
        }
        __syncthreads();

        frag_ab a_h[4], b_h[4];
#pragma unroll
        for (int i = 0; i < 4; ++i) {
            const int ra = wr * 64 + i * 16 + lr;
            a_h[i] = *(const frag_ab*)&Ah[lg][ra ^ (lg << 1)][0];
            const int rb = wc * 64 + i * 16 + lr;
            b_h[i] = *(const frag_ab*)&Wh[lg][rb ^ (lg << 1)][0];
        }
#pragma unroll
        for (int i = 0; i < 4; ++i)
#pragma unroll
            for (int j = 0; j < 4; ++j)
                acc[i][j] = __builtin_amdgcn_mfma_f32_16x16x32_bf16(a_h[i], b_h[j], acc[i][j], 0, 0, 0);
        __syncthreads();
    }

#pragma unroll
    for (int j = 0; j < 4; ++j) {
        const int gc = bm + wc * 64 + j * 16 + lr;
        const float bj = bias[gc];
#pragma unroll
        for (int i = 0; i < 4; ++i) {
            const int grb = bn + wr * 64 + i * 16 + lg * 4;
#pragma unroll
            for (int r = 0; r < 4; ++r) {
                const int gr = grb + r;
                if (gr < N) {
                    float o = acc[i][j][r] + bj;
                    if (RELU) o = fmaxf(o, 0.f);
                    if (OUT == 2)      ((u8*)Yv)[(size_t)gr * M + gc] = f2fp8(o);
                    else if (OUT == 1) ((u16*)Yv)[(size_t)gr * M + gc] = f2bf(o);
                    else               ((float*)Yv)[(size_t)gr * M + gc] = o;
                }
            }
        }
    }
}

// ---------------- weight-stationary fused GRU, transposed, 16 rows/wave (R14) ----------------

template<bool XCAT>
__global__ __launch_bounds__(512)
void gru_ws16(const u16* __restrict__ X, const u16* __restrict__ X2,
              const u16* __restrict__ Hin, u16* __restrict__ Hout,
              const u16* __restrict__ Wih, const u16* __restrict__ Whh,
              const float* __restrict__ bih, const float* __restrict__ bmsg,
              const float* __restrict__ bhh, const int* __restrict__ ideg,
              int N, int nrb) {
    constexpr int KX = XCAT ? 256 : 128;
    constexpr int KX8 = KX / 8;
    __shared__ u16 Wih_s[96 * KX];    // XCAT 48KB else 24KB
    __shared__ u16 Whh_s[96 * 128];   // 24KB

    const int b = blockIdx.x;
    const int xcd = b & 7;
    const int t  = b >> 3;
    const int cg = t & 3;
    const int rowblk = xcd + 8 * (t >> 2);
    if (rowblk >= nrb) return;        // uniform early-out (before any barrier)

    const int tid = threadIdx.x;
    const int wid = tid >> 6;
    const int l = tid & 63;
    const int lr = l & 15, lg = l >> 4;
    const int rw = rowblk * 128 + wid * 16;   // wave's 16 rows

    // ---- stage weight slice into LDS ----
    for (int s = tid; s < 96 * KX8; s += 512) {
        int rloc = s / KX8, k8 = s % KX8;
        int grow = (rloc >> 5) * 128 + cg * 32 + (rloc & 31);
        *(us8*)&Wih_s[rloc * KX + ((k8 ^ (rloc & 7)) << 3)] =
            *(const us8*)(Wih + (size_t)grow * KX + k8 * 8);
    }
    for (int s = tid; s < 96 * 16; s += 512) {
        int rloc = s >> 4, k8 = s & 15;
        int grow = (rloc >> 5) * 128 + cg * 32 + (rloc & 31);
        *(us8*)&Whh_s[rloc * 128 + ((k8 ^ (rloc & 7)) << 3)] =
            *(const us8*)(Whh + (size_t)grow * 128 + k8 * 8);
    }
    __syncthreads();
    if (rw >= N) return;   // no further barriers below

    const int ra0 = rw + lr;

    f32x4 ai[6], ah[6];
#pragma unroll
    for (int j = 0; j < 6; ++j) {
        ai[j] = (f32x4){0.f, 0.f, 0.f, 0.f};
        ah[j] = (f32x4){0.f, 0.f, 0.f, 0.f};
    }

    // ---- Wih @ X^T ----
#pragma unroll
    for (int ks = 0; ks < KX / 32; ++ks) {
        us8 v0 = (us8)0;
        if (XCAT && ks >= 4) {
            const int k = (ks - 4) * 32 + lg * 8;
            if (ra0 < N) v0 = *(const us8*)(X2 + (size_t)(ra0 ^ 1) * 128 + k);
        } else {
            const int k = ks * 32 + lg * 8;
            if (ra0 < N) v0 = *(const us8*)(X + (size_t)ra0 * 128 + k);
        }
        frag_ab x0 = *(const frag_ab*)&v0;
        const int k8 = ks * 4 + lg;
#pragma unroll
        for (int j = 0; j < 6; ++j) {
            const int rloc = j * 16 + lr;
            frag_ab wfr = *(const frag_ab*)&Wih_s[rloc * KX + ((k8 ^ (rloc & 7)) << 3)];
            ai[j] = __builtin_amdgcn_mfma_f32_16x16x32_bf16(wfr, x0, ai[j], 0, 0, 0);
        }
    }
    // ---- Whh @ H^T ----
#pragma unroll
    for (int ks = 0; ks < 4; ++ks) {
        const int k = ks * 32 + lg * 8;
        us8 v0 = (us8)0;
        if (ra0 < N) v0 = *(const us8*)(Hin + (size_t)ra0 * 128 + k);
        frag_ab h0 = *(const frag_ab*)&v0;
        const int k8 = ks * 4 + lg;
#pragma unroll
        for (int j = 0; j < 6; ++j) {
            const int rloc = j * 16 + lr;
            frag_ab wfr = *(const frag_ab*)&Whh_s[rloc * 128 + ((k8 ^ (rloc & 7)) << 3)];
            ah[j] = __builtin_amdgcn_mfma_f32_16x16x32_bf16(wfr, h0, ah[j], 0, 0, 0);
        }
    }

    // ---- gate combine + writeback ----
    const int row0 = rw + lr;
    if (row0 >= N) return;
    const bool hd = ideg[row0] > 0;
#pragma unroll
    for (int dh = 0; dh < 2; ++dh) {
        const int d = cg * 32 + dh * 16 + lg * 4;
        const f32x4 bi_r = *(const f32x4*)&bih[d];
        const f32x4 bh_r = *(const f32x4*)&bhh[d];
        const f32x4 bm_r = *(const f32x4*)&bmsg[d];
        const f32x4 bi_z = *(const f32x4*)&bih[128 + d];
        const f32x4 bh_z = *(const f32x4*)&bhh[128 + d];
        const f32x4 bm_z = *(const f32x4*)&bmsg[128 + d];
        const f32x4 bi_n = *(const f32x4*)&bih[256 + d];
        const f32x4 bh_n = *(const f32x4*)&bhh[256 + d];
        const f32x4 bm_n = *(const f32x4*)&bmsg[256 + d];
        const us4 hv4 = *(const us4*)(Hin + (size_t)row0 * 128 + d);
        us4 o4;
#pragma unroll
        for (int r = 0; r < 4; ++r) {
            float rp = ai[0 + dh][r] + bi_r[r] + (hd ? bm_r[r] : 0.f)
                     + ah[0 + dh][r] + bh_r[r];
            float zp = ai[2 + dh][r] + bi_z[r] + (hd ? bm_z[r] : 0.f)
                     + ah[2 + dh][r] + bh_z[r];
            float np_i = ai[4 + dh][r] + bi_n[r] + (hd ? bm_n[r] : 0.f);
            float np_h = ah[4 + dh][r] + bh_n[r];
            float rg = fsigmoid_(rp);
            float zg = fsigmoid_(zp);
            float ng = ftanh_(np_i + rg * np_h);
            float hv = bf2f(hv4[r]);
            o4[r] = f2bf((1.f - zg) * ng + zg * hv);
        }
        *(us4*)(Hout + (size_t)row0 * 128 + d) = o4;
    }
}

// ---------------- CSR gather: fp8 msg in, bf16 hagg out ----------------
// XCD swizzle keyed to 128-row units (matches gru_ws16 reader).

__global__ void gather_kernel(const u8* __restrict__ msg, const int* __restrict__ off,
                              const int* __restrict__ edges, u16* __restrict__ ohi, int n) {
    const int x = blockIdx.x & 7, t = blockIdx.x >> 3;
    const int s = t & 31, q = t >> 5;
    const int row = ((x + 8 * q) << 7) + s * 4 + (threadIdx.x >> 6);
    if (row >= n) return;
    int lane = threadIdx.x & 63;
    int s0 = off[row], e0 = off[row + 1];
    float ax = 0.f, ay = 0.f;
    for (int i = s0; i < e0; ++i) {
        const ushort w = *(const ushort*)(msg + (size_t)edges[i] * DD + 2 * lane);
        ax += fp82f((u8)(w & 0xFF));
        ay += fp82f((u8)(w >> 8));
    }
    float sc = __builtin_amdgcn_rcpf((float)((e0 - s0) > 0 ? (e0 - s0) : 1));
    *(ushort2*)(ohi + (size_t)row * DD + 2 * lane) = make_ushort2(f2bf(ax * sc), f2bf(ay * sc));
}

// ---------------- readout ----------------

__global__ __launch_bounds__(256)
void logit2_kernel(const float* __restrict__ hidden, const float* __restrict__ w2,
                   const int* __restrict__ l_batch,
                   float* __restrict__ gsum, float* __restrict__ gcnt, int Lc) {
    __shared__ float s_sum[BB];
    __shared__ float s_cnt[BB];
    const int tid = threadIdx.x;
    if (tid < BB) { s_sum[tid] = 0.f; s_cnt[tid] = 0.f; }
    __syncthreads();
    const int lane = tid & 63;
    const int gw = blockIdx.x * 4 + (tid >> 6);
    const int nw = gridDim.x * 4;
    const float2 wv = ((const float2*)w2)[lane];
    for (int row = gw; row < Lc; row += nw) {
        float2 h = ((const float2*)(hidden + (size_t)row * DD))[lane];
        float dp = h.x * wv.x + h.y * wv.y;
#pragma unroll
        for (int off = 32; off > 0; off >>= 1) dp += __shfl_down(dp, off);
        if (lane == 0) {
            int b = l_batch[row];
            atomicAdd(&s_sum[b], dp);
            atomicAdd(&s_cnt[b], 1.0f);
        }
    }
    __syncthreads();
    if (tid < BB) {
        atomicAdd(&gsum[tid], s_sum[tid]);
        atomicAdd(&gcnt[tid], s_cnt[tid]);
    }
}

__global__ void final_kernel(const float* __restrict__ gsum, const float* __restrict__ gcnt,
                             const float* __restrict__ b2, float* __restrict__ out) {
    int b = threadIdx.x;
    if (b < BB) {
        float m = gsum[b] / fmaxf(gcnt[b], 1.0f) + b2[0];
        out[b] = 1.0f / (1.0f + expf(-m));
    }
}

// ---------------- host side ----------------

static inline size_t align_up_(size_t x) { return (x + 255) & ~(size_t)255; }

extern "C" void kernel_launch(void* const* d_in, const int* in_sizes, int n_in,
                              void* d_out, int out_size, void* d_ws, size_t ws_size,
                              hipStream_t stream) {
    const int*   l_ei     = (const int*)d_in[0];
    const int*   c_ei     = (const int*)d_in[1];
    const int*   l_batch  = (const int*)d_in[2];
    const float* l_init   = (const float*)d_in[3];
    const float* c_init   = (const float*)d_in[4];
    const float* l2c_w1   = (const float*)d_in[5];
    const float* l2c_b1   = (const float*)d_in[6];
    const float* l2c_w2   = (const float*)d_in[7];
    const float* l2c_b2   = (const float*)d_in[8];
    const float* c2l_w1   = (const float*)d_in[9];
    const float* c2l_b1   = (const float*)d_in[10];
    const float* c2l_w2   = (const float*)d_in[11];
    const float* c2l_b2   = (const float*)d_in[12];
    const float* cgru_wih = (const float*)d_in[13];
    const float* cgru_whh = (const float*)d_in[14];
    const float* cgru_bih = (const float*)d_in[15];
    const float* cgru_bhh = (const float*)d_in[16];
    const float* lgru_wih = (const float*)d_in[17];
    const float* lgru_whh = (const float*)d_in[18];
    const float* lgru_bih = (const float*)d_in[19];
    const float* lgru_bhh = (const float*)d_in[20];
    const float* ro_w1    = (const float*)d_in[21];
    const float* ro_b1    = (const float*)d_in[22];
    const float* ro_w2    = (const float*)d_in[23];
    const float* ro_b2    = (const float*)d_in[24];

    const int E  = in_sizes[0];
    const int Lc = in_sizes[2];
    const int C  = CC;
    const int NMAX = (C > Lc ? C : Lc);

    // ---- workspace carve (~160 MB) ----
    char* p = (char*)d_ws;
    auto carve = [&](size_t bytes) { void* r = (void*)p; p += align_up_(bytes); return r; };
    u16*   l_embA  = (u16*)carve((size_t)Lc * DD * 2);
    u16*   l_embB  = (u16*)carve((size_t)Lc * DD * 2);
    u16*   c_embA  = (u16*)carve((size_t)C * DD * 2);
    u16*   c_embB  = (u16*)carve((size_t)C * DD * 2);
    u16*   hagg    = (u16*)carve((size_t)NMAX * DD * 2);
    u8*    msg     = (u8*)carve((size_t)NMAX * DD);        // fp8 e4m3
    float* hiddenf = (float*)carve((size_t)Lc * DD * 4);
    int*   ideg_l  = (int*)carve((size_t)Lc * 4);
    int*   ideg_c  = (int*)carve((size_t)C * 4);
    int*   l_off   = (int*)carve((size_t)(Lc + 1) * 4);
    int*   c_off   = (int*)carve((size_t)(C + 1) * 4);
    int*   l_edges = (int*)carve((size_t)E * 4);
    int*   c_edges = (int*)carve((size_t)E * 4);
    int*   filll   = (int*)carve((size_t)Lc * 4);
    int*   fillc   = (int*)carve((size_t)C * 4);
    int*   bsums   = (int*)carve(64 * 4);
    float* Wf_c    = (float*)carve((size_t)384 * 128 * 4);
    float* Wcat    = (float*)carve((size_t)384 * 256 * 4);
    float* bmsg_c  = (float*)carve(384 * 4);
    float* bmsg_l  = (float*)carve(384 * 4);
    u16* w_l2c1 = (u16*)carve(128 * 128 * 2);
    u16* w_c2l1 = (u16*)carve(128 * 128 * 2);
    u16* w_ro1  = (u16*)carve(128 * 128 * 2);
    u16* w_gic  = (u16*)carve(384 * 128 * 2);
    u16* w_ghc  = (u16*)carve(384 * 128 * 2);
    u16* w_ghl  = (u16*)carve(384 * 128 * 2);
    u16* w_gil  = (u16*)carve(384 * 256 * 2);
    float* g_sum = (float*)carve(BB * 4);
    float* g_cnt = (float*)carve(BB * 4);
    (void)ws_size; (void)n_in; (void)out_size;

    // ---- degrees + CSR build ----
    hipMemsetAsync(ideg_l, 0, (size_t)Lc * 4, stream);
    hipMemsetAsync(ideg_c, 0, (size_t)C * 4, stream);
    hipMemsetAsync(filll, 0, (size_t)Lc * 4, stream);
    hipMemsetAsync(fillc, 0, (size_t)C * 4, stream);
    ideg_kernel<<<(E + 255) / 256, 256, 0, stream>>>(l_ei, c_ei, ideg_l, ideg_c, E);
    {
        int nbc = (C + 4095) / 4096, nbl = (Lc + 4095) / 4096;
        bsum_kernel<<<nbc, 1024, 0, stream>>>(ideg_c, bsums, C);
        scan2_kernel<<<nbc, 1024, 0, stream>>>(ideg_c, bsums, c_off, C, nbc);
        bsum_kernel<<<nbl, 1024, 0, stream>>>(ideg_l, bsums, Lc);
        scan2_kernel<<<nbl, 1024, 0, stream>>>(ideg_l, bsums, l_off, Lc, nbl);
    }
    fill2_kernel<<<(E + 255) / 256, 256, 0, stream>>>(
        l_ei, c_ei, l_off, c_off, filll, fillc, l_edges, c_edges, E);

    // ---- weight folds: Wf_c = cgru_wih @ l2c_w2 ; Wcat = [lgru_wihA @ c2l_w2 | lgru_wihB] ----
    foldw_kernel<<<(384 * 128 + 255) / 256, 256, 0, stream>>>(cgru_wih, 128, l2c_w2, Wf_c, 128, 384);
    foldb_kernel<<<2, 256, 0, stream>>>(cgru_wih, 128, l2c_b2, bmsg_c, 384);
    hipMemcpyAsync(Wcat, lgru_wih, (size_t)384 * 256 * 4, hipMemcpyDeviceToDevice, stream);
    foldw_kernel<<<(384 * 128 + 255) / 256, 256, 0, stream>>>(lgru_wih, 256, c2l_w2, Wcat, 256, 384);
    foldb_kernel<<<2, 256, 0, stream>>>(lgru_wih, 256, c2l_b2, bmsg_l, 384);

    // ---- bf16 weight conversion (one launch) ----
    cvtw_all_kernel<<<(294912 + 255) / 256, 256, 0, stream>>>(
        l2c_w1, w_l2c1, c2l_w1, w_c2l1, ro_w1, w_ro1,
        Wf_c, w_gic, cgru_whh, w_ghc, lgru_whh, w_ghl, Wcat, w_gil);

    // ---- init embeddings (one launch) ----
    init_emb2_kernel<<<(((size_t)(Lc + C) * DD) + 255) / 256, 256, 0, stream>>>(
        l_init, l_embA, Lc * DD, c_init, c_embA, C * DD);

    u16* l_cur = l_embA; u16* l_nxt = l_embB;
    u16* c_cur = c_embA; u16* c_nxt = c_embB;

    const int nrb_c = (C + 127) / 128,  nrbp_c = ((nrb_c + 7) / 8) * 8;   // 128-row blocks
    const int nrb_l = (Lc + 127) / 128, nrbp_l = ((nrb_l + 7) / 8) * 8;
    const int nbrow_c = (C + 127) / 128, nbrow_l = (Lc + 127) / 128;

    for (int it = 0; it < N_ITER; ++it) {
        // ---- literal -> clause ----
        mfma_gemm<true, 2><<<dim3(nrbp_l * 2, 1), 256, 0, stream>>>(
            l_cur, w_l2c1, l2c_b1, msg, Lc, 128, nbrow_l);
        gather_kernel<<<nrbp_c * 32, 256, 0, stream>>>(msg, c_off, c_edges, hagg, C);
        gru_ws16<false><<<nrbp_c * 4, 512, 0, stream>>>(
            hagg, nullptr, c_cur, c_nxt, w_gic, w_ghc, cgru_bih, bmsg_c, cgru_bhh,
            ideg_c, C, nrb_c);
        { u16* t = c_cur; c_cur = c_nxt; c_nxt = t; }

        // ---- clause -> literal ----
        mfma_gemm<true, 2><<<dim3(nrbp_c * 2, 1), 256, 0, stream>>>(
            c_cur, w_c2l1, c2l_b1, msg, C, 128, nbrow_c);
        gather_kernel<<<nrbp_l * 32, 256, 0, stream>>>(msg, l_off, l_edges, hagg, Lc);
        gru_ws16<true><<<nrbp_l * 4, 512, 0, stream>>>(
            hagg, l_cur, l_cur, l_nxt, w_gil, w_ghl, lgru_bih, bmsg_l, lgru_bhh,
            ideg_l, Lc, nrb_l);
        { u16* t = l_cur; l_cur = l_nxt; l_nxt = t; }
    }

    // ---- readout ----
    mfma_gemm<true, 0><<<dim3(nrbp_l * 2, 1), 256, 0, stream>>>(
        l_cur, w_ro1, ro_b1, hiddenf, Lc, 128, nbrow_l);
    hipMemsetAsync(g_sum, 0, BB * 4, stream);
    hipMemsetAsync(g_cnt, 0, BB * 4, stream);
    logit2_kernel<<<1024, 256, 0, stream>>>(hiddenf, ro_w2, l_batch, g_sum, g_cnt, Lc);
    final_kernel<<<1, 64, 0, stream>>>(g_sum, g_cnt, ro_b2, (float*)d_out);
}

// Round 16
// 1064.472 us; speedup vs baseline: 1.0958x; 1.0958x over previous
//
#include <hip/hip_runtime.h>
#include <hip/hip_bf16.h>

#define DD 128
#define CC 100000
#define BB 32
#define N_ITER 4
#define INV_INIT_NORM 0.125f   // 1/(sqrt(128)/sqrt(2)) = 1/8

typedef unsigned short u16;
typedef __attribute__((ext_vector_type(8))) short  frag_ab;   // 8 bf16 (4 VGPRs)
typedef __attribute__((ext_vector_type(4))) float  f32x4;
typedef __attribute__((ext_vector_type(8))) unsigned short us8;
typedef __attribute__((ext_vector_type(4))) unsigned short us4;

__device__ __forceinline__ u16 f2bf(float f) {
    union { float f; unsigned u; } v; v.f = f;
    unsigned r = v.u + 0x7fff + ((v.u >> 16) & 1);   // RNE
    return (u16)(r >> 16);
}
__device__ __forceinline__ float bf2f(u16 h) {
    union { unsigned u; float f; } v; v.u = ((unsigned)h) << 16;
    return v.f;
}
// fast HW transcendentals: v_exp_f32 + v_rcp_f32
__device__ __forceinline__ float fsigmoid_(float x) {
    return __builtin_amdgcn_rcpf(1.0f + __expf(-x));
}
__device__ __forceinline__ float ftanh_(float x) {
    return 1.0f - 2.0f * __builtin_amdgcn_rcpf(1.0f + __expf(2.0f * x));
}

// ---------------- precompute: degrees / hierarchical scan / CSR fill ----------------

__global__ void ideg_kernel(const int* __restrict__ li, const int* __restrict__ ci,
                            int* __restrict__ idl, int* __restrict__ idc, int E) {
    int e = blockIdx.x * 256 + threadIdx.x;
    if (e < E) {
        atomicAdd(&idl[li[e]], 1);
        atomicAdd(&idc[ci[e]], 1);
    }
}

__global__ __launch_bounds__(1024)
void bsum_kernel(const int* __restrict__ deg, int* __restrict__ bsum, int n) {
    __shared__ int wred[16];
    const int tid = threadIdx.x, lane = tid & 63, wid = tid >> 6;
    int idx = blockIdx.x * 4096 + tid * 4;
    int s = 0;
#pragma unroll
    for (int j = 0; j < 4; ++j) if (idx + j < n) s += deg[idx + j];
#pragma unroll
    for (int o = 32; o > 0; o >>= 1) s += __shfl_down(s, o);
    if (lane == 0) wred[wid] = s;
    __syncthreads();
    if (tid == 0) {
        int t = 0;
#pragma unroll
        for (int k = 0; k < 16; ++k) t += wred[k];
        bsum[blockIdx.x] = t;
    }
}

__global__ __launch_bounds__(1024)
void scan2_kernel(const int* __restrict__ deg, const int* __restrict__ bsum,
                  int* __restrict__ off, int n, int nb) {
    __shared__ int wsum[16];
    __shared__ int carry_s;
    const int tid = threadIdx.x, lane = tid & 63, wid = tid >> 6;
    if (tid == 0) {
        int c = 0;
        for (int b = 0; b < blockIdx.x; ++b) c += bsum[b];
        carry_s = c;
    }
    int idx = blockIdx.x * 4096 + tid * 4;
    int v0 = idx     < n ? deg[idx]     : 0;
    int v1 = idx + 1 < n ? deg[idx + 1] : 0;
    int v2 = idx + 2 < n ? deg[idx + 2] : 0;
    int v3 = idx + 3 < n ? deg[idx + 3] : 0;
    int t = v0 + v1 + v2 + v3;
    int s = t;
#pragma unroll
    for (int o = 1; o < 64; o <<= 1) { int u = __shfl_up(s, o); if (lane >= o) s += u; }
    if (lane == 63) wsum[wid] = s;
    __syncthreads();
    if (wid == 0 && lane < 16) {
        int x = wsum[lane];
#pragma unroll
        for (int o = 1; o < 16; o <<= 1) { int u = __shfl_up(x, o); if (lane >= o) x += u; }
        wsum[lane] = x;
    }
    __syncthreads();
    int woff = (wid > 0) ? wsum[wid - 1] : 0;
    int excl = carry_s + woff + s - t;
    if (idx     < n) off[idx]     = excl;
    if (idx + 1 < n) off[idx + 1] = excl + v0;
    if (idx + 2 < n) off[idx + 2] = excl + v0 + v1;
    if (idx + 3 < n) off[idx + 3] = excl + v0 + v1 + v2;
    if (blockIdx.x == nb - 1 && tid == 0) off[n] = carry_s + wsum[15];
}

// both CSR fills in one launch
__global__ void fill2_kernel(const int* __restrict__ li, const int* __restrict__ ci,
                             const int* __restrict__ l_off, const int* __restrict__ c_off,
                             int* __restrict__ filll, int* __restrict__ fillc,
                             int* __restrict__ l_edges, int* __restrict__ c_edges, int E) {
    int e = blockIdx.x * 256 + threadIdx.x;
    if (e < E) {
        int l = li[e], c = ci[e];
        int pc = atomicAdd(&fillc[c], 1);
        c_edges[c_off[c] + pc] = l;
        int pl = atomicAdd(&filll[l], 1);
        l_edges[l_off[l] + pl] = c;
    }
}

// ---------------- precompute: weight folds / bf16 conversion ----------------

__global__ void foldw_kernel(const float* __restrict__ wih, int ldw,
                             const float* __restrict__ w2,
                             float* __restrict__ out, int out_ld, int M) {
    int idx = blockIdx.x * 256 + threadIdx.x;
    if (idx >= M * 128) return;
    int o = idx >> 7, k = idx & 127;
    float s = 0.f;
    for (int m = 0; m < 128; ++m) s += wih[(size_t)o * ldw + m] * w2[m * 128 + k];
    out[(size_t)o * out_ld + k] = s;
}

__global__ void foldb_kernel(const float* __restrict__ wih, int ldw,
                             const float* __restrict__ b2,
                             float* __restrict__ out, int M) {
    int o = blockIdx.x * 256 + threadIdx.x;
    if (o >= M) return;
    float s = 0.f;
    for (int m = 0; m < 128; ++m) s += wih[(size_t)o * ldw + m] * b2[m];
    out[o] = s;
}

// all 7 bf16 weight conversions in one launch
__global__ void cvtw_all_kernel(const float* __restrict__ s0, u16* __restrict__ d0,
                                const float* __restrict__ s1, u16* __restrict__ d1,
                                const float* __restrict__ s2, u16* __restrict__ d2,
                                const float* __restrict__ s3, u16* __restrict__ d3,
                                const float* __restrict__ s4, u16* __restrict__ d4,
                                const float* __restrict__ s5, u16* __restrict__ d5,
                                const float* __restrict__ s6, u16* __restrict__ d6) {
    int i = blockIdx.x * 256 + threadIdx.x;
    if      (i < 16384)   d0[i] = f2bf(s0[i]);
    else if (i < 32768)   d1[i - 16384] = f2bf(s1[i - 16384]);
    else if (i < 49152)   d2[i - 32768] = f2bf(s2[i - 32768]);
    else if (i < 98304)   d3[i - 49152] = f2bf(s3[i - 49152]);
    else if (i < 147456)  d4[i - 98304] = f2bf(s4[i - 98304]);
    else if (i < 196608)  d5[i - 147456] = f2bf(s5[i - 147456]);
    else if (i < 294912)  d6[i - 196608] = f2bf(s6[i - 196608]);
}

// both embedding inits in one launch
__global__ void init_emb2_kernel(const float* __restrict__ li, u16* __restrict__ lo, int nl,
                                 const float* __restrict__ ci, u16* __restrict__ co, int nc) {
    int i = blockIdx.x * 256 + threadIdx.x;
    if (i < nl) lo[i] = f2bf(li[i & (DD - 1)] * INV_INIT_NORM);
    else if (i < nl + nc) { int j = i - nl; co[j] = f2bf(ci[j & (DD - 1)] * INV_INIT_NORM); }
}

// ---------------- bf16 MFMA GEMM (msg MLP + readout) ----------------
// XCD-aware row swizzle (R11): brow = (xcd + 8q)*2 + s.

template<bool RELU, bool OUTBF16>
__global__ __launch_bounds__(256)
void mfma_gemm(const u16* __restrict__ Ahi, const u16* __restrict__ Whi,
               const float* __restrict__ bias, void* __restrict__ Yv, int N, int M,
               int nbrow) {
    __shared__ u16 Ah[4][128][8], Wh[4][128][8];

    const int xcd = blockIdx.x & 7, tt = blockIdx.x >> 3;
    const int s2 = tt & 1, q = tt >> 1;
    const int brow = (xcd + 8 * q) * 2 + s2;
    if (brow >= nbrow) return;   // uniform early-out before any barrier

    const int tid = threadIdx.x;
    const int bn = brow * 128, bm = blockIdx.y * 128;
    const int l = tid & 63, w = tid >> 6;
    const int wr = w >> 1, wc = w & 1;
    const int lr = l & 15, lg = l >> 4;

    f32x4 acc[4][4];
#pragma unroll
    for (int i = 0; i < 4; ++i)
#pragma unroll
        for (int j = 0; j < 4; ++j) acc[i][j] = (f32x4){0.f, 0.f, 0.f, 0.f};

    for (int k0 = 0; k0 < 128; k0 += 32) {
#pragma unroll
        for (int t = 0; t < 2; ++t) {
            const int slot = t * 256 + tid;
            const int row = slot >> 2, g = slot & 3, rs = row ^ (g << 1);
            const int gr = bn + row;
            us8 vh = (us8)0;
            if (gr < N) vh = *(const us8*)(Ahi + (size_t)gr * 128 + k0 + g * 8);
            *(us8*)&Ah[g][rs][0] = vh;
            *(us8*)&Wh[g][rs][0] = *(const us8*)(Whi + (size_t)(bm + row) * 128 + k0 + g * 8);
        }
        __syncthreads();

        frag_ab a_h[4], b_h[4];
#pragma unroll
        for (int i = 0; i < 4; ++i) {
            const int ra = wr * 64 + i * 16 + lr;
            a_h[i] = *(const frag_ab*)&Ah[lg][ra ^ (lg << 1)][0];
            const int rb = wc * 64 + i * 16 + lr;
            b_h[i] = *(const frag_ab*)&Wh[lg][rb ^ (lg << 1)][0];
        }
#pragma unroll
        for (int i = 0; i < 4; ++i)
#pragma unroll
            for (int j = 0; j < 4; ++j)
                acc[i][j] = __builtin_amdgcn_mfma_f32_16x16x32_bf16(a_h[i], b_h[j], acc[i][j], 0, 0, 0);
        __syncthreads();
    }

#pragma unroll
    for (int j = 0; j < 4; ++j) {
        const int gc = bm + wc * 64 + j * 16 + lr;
        const float bj = bias[gc];
#pragma unroll
        for (int i = 0; i < 4; ++i) {
            const int grb = bn + wr * 64 + i * 16 + lg * 4;
#pragma unroll
            for (int r = 0; r < 4; ++r) {
                const int gr = grb + r;
                if (gr < N) {
                    float o = acc[i][j][r] + bj;
                    if (RELU) o = fmaxf(o, 0.f);
                    if (OUTBF16) ((u16*)Yv)[(size_t)gr * M + gc] = f2bf(o);
                    else         ((float*)Yv)[(size_t)gr * M + gc] = o;
                }
            }
        }
    }
}

// ---------------- weight-stationary fused GRU, transposed, 16 rows/wave (R14-proven) ----------------
// Operand-swapped MFMA: acc = mfma(W_frag, X_frag); thread owns 4 consecutive
// dims of one row -> 8B us4 epilogue. Wave owns 16 rows (acc 12 f32x4, 44 VGPR,
// occupancy ~38%). Separate Wih/Whh LDS buffers, ONE barrier. XCD swizzle
// (R8-verified): xcd=b&7, t=b>>3, cg=t&3, rowblk=xcd+8*(t>>2).

template<bool XCAT>
__global__ __launch_bounds__(512)
void gru_ws16(const u16* __restrict__ X, const u16* __restrict__ X2,
              const u16* __restrict__ Hin, u16* __restrict__ Hout,
              const u16* __restrict__ Wih, const u16* __restrict__ Whh,
              const float* __restrict__ bih, const float* __restrict__ bmsg,
              const float* __restrict__ bhh, const int* __restrict__ ideg,
              int N, int nrb) {
    constexpr int KX = XCAT ? 256 : 128;
    constexpr int KX8 = KX / 8;
    __shared__ u16 Wih_s[96 * KX];    // XCAT 48KB else 24KB
    __shared__ u16 Whh_s[96 * 128];   // 24KB

    const int b = blockIdx.x;
    const int xcd = b & 7;
    const int t  = b >> 3;
    const int cg = t & 3;
    const int rowblk = xcd + 8 * (t >> 2);
    if (rowblk >= nrb) return;        // uniform early-out (before any barrier)

    const int tid = threadIdx.x;
    const int wid = tid >> 6;
    const int l = tid & 63;
    const int lr = l & 15, lg = l >> 4;
    const int rw = rowblk * 128 + wid * 16;   // wave's 16 rows

    // ---- stage weight slice into LDS ----
    for (int s = tid; s < 96 * KX8; s += 512) {
        int rloc = s / KX8, k8 = s % KX8;
        int grow = (rloc >> 5) * 128 + cg * 32 + (rloc & 31);
        *(us8*)&Wih_s[rloc * KX + ((k8 ^ (rloc & 7)) << 3)] =
            *(const us8*)(Wih + (size_t)grow * KX + k8 * 8);
    }
    for (int s = tid; s < 96 * 16; s += 512) {
        int rloc = s >> 4, k8 = s & 15;
        int grow = (rloc >> 5) * 128 + cg * 32 + (rloc & 31);
        *(us8*)&Whh_s[rloc * 128 + ((k8 ^ (rloc & 7)) << 3)] =
            *(const us8*)(Whh + (size_t)grow * 128 + k8 * 8);
    }
    __syncthreads();
    if (rw >= N) return;   // no further barriers below

    const int ra0 = rw + lr;

    f32x4 ai[6], ah[6];
#pragma unroll
    for (int j = 0; j < 6; ++j) {
        ai[j] = (f32x4){0.f, 0.f, 0.f, 0.f};
        ah[j] = (f32x4){0.f, 0.f, 0.f, 0.f};
    }

    // ---- Wih @ X^T ----
#pragma unroll
    for (int ks = 0; ks < KX / 32; ++ks) {
        us8 v0 = (us8)0;
        if (XCAT && ks >= 4) {
            const int k = (ks - 4) * 32 + lg * 8;
            if (ra0 < N) v0 = *(const us8*)(X2 + (size_t)(ra0 ^ 1) * 128 + k);
        } else {
            const int k = ks * 32 + lg * 8;
            if (ra0 < N) v0 = *(const us8*)(X + (size_t)ra0 * 128 + k);
        }
        frag_ab x0 = *(const frag_ab*)&v0;
        const int k8 = ks * 4 + lg;
#pragma unroll
        for (int j = 0; j < 6; ++j) {
            const int rloc = j * 16 + lr;
            frag_ab wfr = *(const frag_ab*)&Wih_s[rloc * KX + ((k8 ^ (rloc & 7)) << 3)];
            ai[j] = __builtin_amdgcn_mfma_f32_16x16x32_bf16(wfr, x0, ai[j], 0, 0, 0);
        }
    }
    // ---- Whh @ H^T ----
#pragma unroll
    for (int ks = 0; ks < 4; ++ks) {
        const int k = ks * 32 + lg * 8;
        us8 v0 = (us8)0;
        if (ra0 < N) v0 = *(const us8*)(Hin + (size_t)ra0 * 128 + k);
        frag_ab h0 = *(const frag_ab*)&v0;
        const int k8 = ks * 4 + lg;
#pragma unroll
        for (int j = 0; j < 6; ++j) {
            const int rloc = j * 16 + lr;
            frag_ab wfr = *(const frag_ab*)&Whh_s[rloc * 128 + ((k8 ^ (rloc & 7)) << 3)];
            ah[j] = __builtin_amdgcn_mfma_f32_16x16x32_bf16(wfr, h0, ah[j], 0, 0, 0);
        }
    }

    // ---- gate combine + writeback (transposed D: thread owns row rw+lr,
    //      dims d..d+3, d = cg*32 + dh*16 + lg*4) ----
    const int row0 = rw + lr;
    if (row0 >= N) return;
    const bool hd = ideg[row0] > 0;
#pragma unroll
    for (int dh = 0; dh < 2; ++dh) {
        const int d = cg * 32 + dh * 16 + lg * 4;
        const f32x4 bi_r = *(const f32x4*)&bih[d];
        const f32x4 bh_r = *(const f32x4*)&bhh[d];
        const f32x4 bm_r = *(const f32x4*)&bmsg[d];
        const f32x4 bi_z = *(const f32x4*)&bih[128 + d];
        const f32x4 bh_z = *(const f32x4*)&bhh[128 + d];
        const f32x4 bm_z = *(const f32x4*)&bmsg[128 + d];
        const f32x4 bi_n = *(const f32x4*)&bih[256 + d];
        const f32x4 bh_n = *(const f32x4*)&bhh[256 + d];
        const f32x4 bm_n = *(const f32x4*)&bmsg[256 + d];
        const us4 hv4 = *(const us4*)(Hin + (size_t)row0 * 128 + d);
        us4 o4;
#pragma unroll
        for (int r = 0; r < 4; ++r) {
            float rp = ai[0 + dh][r] + bi_r[r] + (hd ? bm_r[r] : 0.f)
                     + ah[0 + dh][r] + bh_r[r];
            float zp = ai[2 + dh][r] + bi_z[r] + (hd ? bm_z[r] : 0.f)
                     + ah[2 + dh][r] + bh_z[r];
            float np_i = ai[4 + dh][r] + bi_n[r] + (hd ? bm_n[r] : 0.f);
            float np_h = ah[4 + dh][r] + bh_n[r];
            float rg = fsigmoid_(rp);
            float zg = fsigmoid_(zp);
            float ng = ftanh_(np_i + rg * np_h);
            float hv = bf2f(hv4[r]);
            o4[r] = f2bf((1.f - zg) * ng + zg * hv);
        }
        *(us4*)(Hout + (size_t)row0 * 128 + d) = o4;
    }
}

// ---------------- CSR gather: out[row] = (1/max(deg,1)) * sum msg[src], bf16 ----------------
// XCD swizzle keyed to 128-row units (matches gru_ws16 reader).

__global__ void gather_kernel(const u16* __restrict__ msg, const int* __restrict__ off,
                              const int* __restrict__ edges, u16* __restrict__ ohi, int n) {
    const int x = blockIdx.x & 7, t = blockIdx.x >> 3;
    const int s = t & 31, q = t >> 5;
    const int row = ((x + 8 * q) << 7) + s * 4 + (threadIdx.x >> 6);
    if (row >= n) return;
    int lane = threadIdx.x & 63;
    int s0 = off[row], e0 = off[row + 1];
    float ax = 0.f, ay = 0.f;
    for (int i = s0; i < e0; ++i) {
        const ushort2 v = ((const ushort2*)(msg + (size_t)edges[i] * DD))[lane];
        ax += bf2f(v.x); ay += bf2f(v.y);
    }
    float sc = __builtin_amdgcn_rcpf((float)((e0 - s0) > 0 ? (e0 - s0) : 1));
    *(ushort2*)(ohi + (size_t)row * DD + 2 * lane) = make_ushort2(f2bf(ax * sc), f2bf(ay * sc));
}

// ---------------- readout ----------------

__global__ __launch_bounds__(256)
void logit2_kernel(const float* __restrict__ hidden, const float* __restrict__ w2,
                   const int* __restrict__ l_batch,
                   float* __restrict__ gsum, float* __restrict__ gcnt, int Lc) {
    __shared__ float s_sum[BB];
    __shared__ float s_cnt[BB];
    const int tid = threadIdx.x;
    if (tid < BB) { s_sum[tid] = 0.f; s_cnt[tid] = 0.f; }
    __syncthreads();
    const int lane = tid & 63;
    const int gw = blockIdx.x * 4 + (tid >> 6);
    const int nw = gridDim.x * 4;
    const float2 wv = ((const float2*)w2)[lane];
    for (int row = gw; row < Lc; row += nw) {
        float2 h = ((const float2*)(hidden + (size_t)row * DD))[lane];
        float dp = h.x * wv.x + h.y * wv.y;
#pragma unroll
        for (int off = 32; off > 0; off >>= 1) dp += __shfl_down(dp, off);
        if (lane == 0) {
            int b = l_batch[row];
            atomicAdd(&s_sum[b], dp);
            atomicAdd(&s_cnt[b], 1.0f);
        }
    }
    __syncthreads();
    if (tid < BB) {
        atomicAdd(&gsum[tid], s_sum[tid]);
        atomicAdd(&gcnt[tid], s_cnt[tid]);
    }
}

__global__ void final_kernel(const float* __restrict__ gsum, const float* __restrict__ gcnt,
                             const float* __restrict__ b2, float* __restrict__ out) {
    int b = threadIdx.x;
    if (b < BB) {
        float m = gsum[b] / fmaxf(gcnt[b], 1.0f) + b2[0];
        out[b] = 1.0f / (1.0f + expf(-m));
    }
}

// ---------------- host side ----------------

static inline size_t align_up_(size_t x) { return (x + 255) & ~(size_t)255; }

extern "C" void kernel_launch(void* const* d_in, const int* in_sizes, int n_in,
                              void* d_out, int out_size, void* d_ws, size_t ws_size,
                              hipStream_t stream) {
    const int*   l_ei     = (const int*)d_in[0];
    const int*   c_ei     = (const int*)d_in[1];
    const int*   l_batch  = (const int*)d_in[2];
    const float* l_init   = (const float*)d_in[3];
    const float* c_init   = (const float*)d_in[4];
    const float* l2c_w1   = (const float*)d_in[5];
    const float* l2c_b1   = (const float*)d_in[6];
    const float* l2c_w2   = (const float*)d_in[7];
    const float* l2c_b2   = (const float*)d_in[8];
    const float* c2l_w1   = (const float*)d_in[9];
    const float* c2l_b1   = (const float*)d_in[10];
    const float* c2l_w2   = (const float*)d_in[11];
    const float* c2l_b2   = (const float*)d_in[12];
    const float* cgru_wih = (const float*)d_in[13];
    const float* cgru_whh = (const float*)d_in[14];
    const float* cgru_bih = (const float*)d_in[15];
    const float* cgru_bhh = (const float*)d_in[16];
    const float* lgru_wih = (const float*)d_in[17];
    const float* lgru_whh = (const float*)d_in[18];
    const float* lgru_bih = (const float*)d_in[19];
    const float* lgru_bhh = (const float*)d_in[20];
    const float* ro_w1    = (const float*)d_in[21];
    const float* ro_b1    = (const float*)d_in[22];
    const float* ro_w2    = (const float*)d_in[23];
    const float* ro_b2    = (const float*)d_in[24];

    const int E  = in_sizes[0];
    const int Lc = in_sizes[2];
    const int C  = CC;
    const int NMAX = (C > Lc ? C : Lc);

    // ---- workspace carve (~171 MB) ----
    char* p = (char*)d_ws;
    auto carve = [&](size_t bytes) { void* r = (void*)p; p += align_up_(bytes); return r; };
    u16*   l_embA  = (u16*)carve((size_t)Lc * DD * 2);
    u16*   l_embB  = (u16*)carve((size_t)Lc * DD * 2);
    u16*   c_embA  = (u16*)carve((size_t)C * DD * 2);
    u16*   c_embB  = (u16*)carve((size_t)C * DD * 2);
    u16*   hagg    = (u16*)carve((size_t)NMAX * DD * 2);
    u16*   msg     = (u16*)carve((size_t)NMAX * DD * 2);
    float* hiddenf = (float*)carve((size_t)Lc * DD * 4);
    int*   ideg_l  = (int*)carve((size_t)Lc * 4);
    int*   ideg_c  = (int*)carve((size_t)C * 4);
    int*   l_off   = (int*)carve((size_t)(Lc + 1) * 4);
    int*   c_off   = (int*)carve((size_t)(C + 1) * 4);
    int*   l_edges = (int*)carve((size_t)E * 4);
    int*   c_edges = (int*)carve((size_t)E * 4);
    int*   filll   = (int*)carve((size_t)Lc * 4);
    int*   fillc   = (int*)carve((size_t)C * 4);
    int*   bsums   = (int*)carve(64 * 4);
    float* Wf_c    = (float*)carve((size_t)384 * 128 * 4);
    float* Wcat    = (float*)carve((size_t)384 * 256 * 4);
    float* bmsg_c  = (float*)carve(384 * 4);
    float* bmsg_l  = (float*)carve(384 * 4);
    u16* w_l2c1 = (u16*)carve(128 * 128 * 2);
    u16* w_c2l1 = (u16*)carve(128 * 128 * 2);
    u16* w_ro1  = (u16*)carve(128 * 128 * 2);
    u16* w_gic  = (u16*)carve(384 * 128 * 2);
    u16* w_ghc  = (u16*)carve(384 * 128 * 2);
    u16* w_ghl  = (u16*)carve(384 * 128 * 2);
    u16* w_gil  = (u16*)carve(384 * 256 * 2);
    float* g_sum = (float*)carve(BB * 4);
    float* g_cnt = (float*)carve(BB * 4);
    (void)ws_size; (void)n_in; (void)out_size;

    // ---- degrees + CSR build ----
    hipMemsetAsync(ideg_l, 0, (size_t)Lc * 4, stream);
    hipMemsetAsync(ideg_c, 0, (size_t)C * 4, stream);
    hipMemsetAsync(filll, 0, (size_t)Lc * 4, stream);
    hipMemsetAsync(fillc, 0, (size_t)C * 4, stream);
    ideg_kernel<<<(E + 255) / 256, 256, 0, stream>>>(l_ei, c_ei, ideg_l, ideg_c, E);
    {
        int nbc = (C + 4095) / 4096, nbl = (Lc + 4095) / 4096;
        bsum_kernel<<<nbc, 1024, 0, stream>>>(ideg_c, bsums, C);
        scan2_kernel<<<nbc, 1024, 0, stream>>>(ideg_c, bsums, c_off, C, nbc);
        bsum_kernel<<<nbl, 1024, 0, stream>>>(ideg_l, bsums, Lc);
        scan2_kernel<<<nbl, 1024, 0, stream>>>(ideg_l, bsums, l_off, Lc, nbl);
    }
    fill2_kernel<<<(E + 255) / 256, 256, 0, stream>>>(
        l_ei, c_ei, l_off, c_off, filll, fillc, l_edges, c_edges, E);

    // ---- weight folds: Wf_c = cgru_wih @ l2c_w2 ; Wcat = [lgru_wihA @ c2l_w2 | lgru_wihB] ----
    foldw_kernel<<<(384 * 128 + 255) / 256, 256, 0, stream>>>(cgru_wih, 128, l2c_w2, Wf_c, 128, 384);
    foldb_kernel<<<2, 256, 0, stream>>>(cgru_wih, 128, l2c_b2, bmsg_c, 384);
    hipMemcpyAsync(Wcat, lgru_wih, (size_t)384 * 256 * 4, hipMemcpyDeviceToDevice, stream);
    foldw_kernel<<<(384 * 128 + 255) / 256, 256, 0, stream>>>(lgru_wih, 256, c2l_w2, Wcat, 256, 384);
    foldb_kernel<<<2, 256, 0, stream>>>(lgru_wih, 256, c2l_b2, bmsg_l, 384);

    // ---- bf16 weight conversion (one launch) ----
    cvtw_all_kernel<<<(294912 + 255) / 256, 256, 0, stream>>>(
        l2c_w1, w_l2c1, c2l_w1, w_c2l1, ro_w1, w_ro1,
        Wf_c, w_gic, cgru_whh, w_ghc, lgru_whh, w_ghl, Wcat, w_gil);

    // ---- init embeddings (one launch) ----
    init_emb2_kernel<<<(((size_t)(Lc + C) * DD) + 255) / 256, 256, 0, stream>>>(
        l_init, l_embA, Lc * DD, c_init, c_embA, C * DD);

    u16* l_cur = l_embA; u16* l_nxt = l_embB;
    u16* c_cur = c_embA; u16* c_nxt = c_embB;

    const int nrb_c = (C + 127) / 128,  nrbp_c = ((nrb_c + 7) / 8) * 8;   // 128-row blocks
    const int nrb_l = (Lc + 127) / 128, nrbp_l = ((nrb_l + 7) / 8) * 8;
    const int nbrow_c = (C + 127) / 128, nbrow_l = (Lc + 127) / 128;

    for (int it = 0; it < N_ITER; ++it) {
        // ---- literal -> clause ----
        mfma_gemm<true, true><<<dim3(nrbp_l * 2, 1), 256, 0, stream>>>(
            l_cur, w_l2c1, l2c_b1, msg, Lc, 128, nbrow_l);
        gather_kernel<<<nrbp_c * 32, 256, 0, stream>>>(msg, c_off, c_edges, hagg, C);
        gru_ws16<false><<<nrbp_c * 4, 512, 0, stream>>>(
            hagg, nullptr, c_cur, c_nxt, w_gic, w_ghc, cgru_bih, bmsg_c, cgru_bhh,
            ideg_c, C, nrb_c);
        { u16* t = c_cur; c_cur = c_nxt; c_nxt = t; }

        // ---- clause -> literal ----
        mfma_gemm<true, true><<<dim3(nrbp_c * 2, 1), 256, 0, stream>>>(
            c_cur, w_c2l1, c2l_b1, msg, C, 128, nbrow_c);
        gather_kernel<<<nrbp_l * 32, 256, 0, stream>>>(msg, l_off, l_edges, hagg, Lc);
        gru_ws16<true><<<nrbp_l * 4, 512, 0, stream>>>(
            hagg, l_cur, l_cur, l_nxt, w_gil, w_ghl, lgru_bih, bmsg_l, lgru_bhh,
            ideg_l, Lc, nrb_l);
        { u16* t = l_cur; l_cur = l_nxt; l_nxt = t; }
    }

    // ---- readout ----
    mfma_gemm<true, false><<<dim3(nrbp_l * 2, 1), 256, 0, stream>>>(
        l_cur, w_ro1, ro_b1, hiddenf, Lc, 128, nbrow_l);
    hipMemsetAsync(g_sum, 0, BB * 4, stream);
    hipMemsetAsync(g_cnt, 0, BB * 4, stream);
    logit2_kernel<<<1024, 256, 0, stream>>>(hiddenf, ro_w2, l_batch, g_sum, g_cnt, Lc);
    final_kernel<<<1, 64, 0, stream>>>(g_sum, g_cnt, ro_b2, (float*)d_out);
}